// Round 14
// baseline (1424.627 us; speedup 1.0000x reference)
//
#include <hip/hip_runtime.h>

typedef unsigned short u16;
typedef __attribute__((ext_vector_type(4))) float f32x4;
typedef __attribute__((ext_vector_type(8))) short s16x8;
typedef __attribute__((ext_vector_type(4))) short s16x4;
typedef __attribute__((ext_vector_type(4))) unsigned short u16x4;

#define HH 12
#define CC 768
#define AS1(p) ((const __attribute__((address_space(1))) void*)(p))
#define AS3(p) ((__attribute__((address_space(3))) void*)(p))

__device__ inline u16 f2bf(float x){
  unsigned u = __float_as_uint(x);
  u = (u + 0x7FFFu + ((u >> 16) & 1u)) >> 16;
  return (u16)u;
}

__device__ inline f32x4 mfma32(s16x8 a, s16x8 b, f32x4 c){
  return __builtin_amdgcn_mfma_f32_16x16x32_bf16(a, b, c, 0, 0, 0);
}
__device__ inline f32x4 mfma16(s16x4 a, s16x4 b, f32x4 c){
  return __builtin_amdgcn_mfma_f32_16x16x16bf16_1k(a, b, c, 0, 0, 0);
}

__device__ inline void xcd_remap(int gx, int gy, int& bx, int& by){
  int nwg = gx*gy;
  int orig = blockIdx.x + gx*blockIdx.y;
  int q = nwg >> 3, r8 = nwg & 7;
  int xcd = orig & 7, off = orig >> 3;
  int wg = (xcd < r8 ? xcd*(q+1) : r8*(q+1) + (xcd-r8)*q) + off;
  bx = wg / gy; by = wg - bx*gy;
}

// ---------------- weight fp32 [K,N] -> bf16 [N,K] (per blockIdx.z set) ----------------
__global__ void wtrans(const float* __restrict__ W, u16* __restrict__ Wt, int K, int N){
  __shared__ float tile[32][33];
  int k0 = blockIdx.x*32, n0 = blockIdx.y*32;
  const float* Wz = W + (size_t)blockIdx.z*K*N;
  u16* Wtz = Wt + (size_t)blockIdx.z*K*N;
  int tx = threadIdx.x & 31, ty = threadIdx.x >> 5;
  #pragma unroll
  for(int r = ty; r < 32; r += 8)
    tile[r][tx] = Wz[(size_t)(k0+r)*N + n0 + tx];
  __syncthreads();
  #pragma unroll
  for(int r = ty; r < 32; r += 8)
    Wtz[(size_t)(n0+r)*K + k0 + tx] = f2bf(tile[tx][r]);
}

// ---------------- scatter RGB/NIR/TIR into concat layout [B,387,C] ----------------
__global__ void initcat(const float* __restrict__ R, const float* __restrict__ Nr,
                        const float* __restrict__ T, float* __restrict__ xcat){
  int idx = blockIdx.x*256 + threadIdx.x;
  const int per = 32*129*768/4;
  if(idx >= per) return;
  int z = blockIdx.y;
  const float* src = z == 0 ? R : (z == 1 ? Nr : T);
  float4 v = ((const float4*)src)[idx];
  int e = idx*4;
  int row = e / 768, c = e - row*768;
  int bb2 = row / 129, nn = row - bb2*129;
  ((float4*)xcat)[((size_t)(bb2*387 + z*129 + nn)*768 + c)/4] = v;
}

__device__ inline float maskval(const float* m, int b, int n){
  return (n == 0) ? 1.0f : m[b*128 + n - 1];
}

// ---------------- LayerNorm * mask : 4 rows per 256-thr block ----------------
template<int F32OUT>
__global__ __launch_bounds__(256) void ln_mask(
    const float* __restrict__ x,
    const float* __restrict__ gg, const float* __restrict__ bb, int zsG,
    const float* __restrict__ mask,
    void* __restrict__ out, size_t zsO,
    int tpb, int zoffmul)
{
  int wid = threadIdx.x >> 6, lane = threadIdx.x & 63;
  int r = blockIdx.x*4 + wid, z = blockIdx.y;
  int bidx = r / tpb, nn = r - bidx*tpb;
  size_t cat = (size_t)bidx*387 + z*zoffmul + nn;
  const float4* xr = (const float4*)(x + cat*CC);
  float4 v[3]; float s = 0.f, sq = 0.f;
  #pragma unroll
  for(int w = 0; w < 3; ++w){
    v[w] = xr[w*64 + lane];
    s  += v[w].x + v[w].y + v[w].z + v[w].w;
    sq += v[w].x*v[w].x + v[w].y*v[w].y + v[w].z*v[w].z + v[w].w*v[w].w;
  }
  #pragma unroll
  for(int o = 32; o; o >>= 1){ s += __shfl_xor(s, o); sq += __shfl_xor(sq, o); }
  float mu = s * (1.f/768.f);
  float var = sq * (1.f/768.f) - mu*mu;
  float rstd = rsqrtf(var + 1e-5f);
  float mv = maskval(mask, bidx, nn % 129);
  const float4* g4 = (const float4*)(gg + (size_t)z*zsG);
  const float4* b4 = (const float4*)(bb + (size_t)z*zsG);
  #pragma unroll
  for(int w = 0; w < 3; ++w){
    float4 gv = g4[w*64+lane], bv = b4[w*64+lane];
    float y0 = ((v[w].x - mu)*rstd*gv.x + bv.x) * mv;
    float y1 = ((v[w].y - mu)*rstd*gv.y + bv.y) * mv;
    float y2 = ((v[w].z - mu)*rstd*gv.z + bv.z) * mv;
    float y3 = ((v[w].w - mu)*rstd*gv.w + bv.w) * mv;
    if(F32OUT){
      ((float4*)out)[cat*(CC/4) + w*64 + lane] = make_float4(y0,y1,y2,y3);
    } else {
      u16x4 p; p.x = f2bf(y0); p.y = f2bf(y1); p.z = f2bf(y2); p.w = f2bf(y3);
      ((u16x4*)((u16*)out + z*zsO + (size_t)r*CC))[w*64 + lane] = p;
    }
  }
}

// ---------------- GEMM 128x128 (single-buf BK=64, swizzle, high TLP; optional split-K) ----------------
// EPI 0: bf16 store ; 1: tanh-gelu bf16 ; 2: residual-add fp32 xcat (atomic when KS>1)
template<int EPI, int TPB, int KS>
__global__ __launch_bounds__(256, 5) void gemm_bt(
    const u16* __restrict__ A, size_t zsA,
    const u16* __restrict__ Bt, size_t zsB,
    void* __restrict__ O, size_t zsO,
    int M, int N, int K,
    int zoffmul)
{
  __shared__ u16 As[128*64];
  __shared__ u16 Bs[128*64];
  int bz = blockIdx.z;
  int z = bz / KS, ks = bz - z*KS;
  int KSL = K / KS;
  const u16* Az = A + zsA*(size_t)z + ks*KSL;
  const u16* Bz = Bt + zsB*(size_t)z + ks*KSL;
  int bx, by; xcd_remap(gridDim.x, gridDim.y, bx, by);
  int m0 = bx*128, n0 = by*128;

  int tid = threadIdx.x, wid = tid >> 6, lane = tid & 63;
  int wr = wid >> 1, wc = wid & 1;
  int lrow = lane & 15, g4 = lane >> 4;

  int srow = tid >> 3;
  int swcol = ((tid & 7) ^ (srow & 7)) * 8;
  const u16 *pa[4], *pb[4];
  #pragma unroll
  for(int i = 0; i < 4; ++i){
    int ra = m0 + srow + i*32; ra = ra < M ? ra : M - 1;
    pa[i] = Az + (size_t)ra*K + swcol;
    pb[i] = Bz + (size_t)(n0 + srow + i*32)*K + swcol;
  }
  int dofs = tid*8;
  int xs0 = ((0*4 + g4) ^ (lrow & 7)) * 8;
  int xs1 = ((1*4 + g4) ^ (lrow & 7)) * 8;

  f32x4 acc[4][4] = {};
  int NT = KSL >> 6;

  for(int t = 0; t < NT; ++t){
    #pragma unroll
    for(int i = 0; i < 4; ++i)
      __builtin_amdgcn_global_load_lds(AS1(pa[i]), AS3(&As[dofs + i*2048]), 16, 0, 0);
    #pragma unroll
    for(int i = 0; i < 4; ++i)
      __builtin_amdgcn_global_load_lds(AS1(pb[i]), AS3(&Bs[dofs + i*2048]), 16, 0, 0);
    #pragma unroll
    for(int i = 0; i < 4; ++i){ pa[i] += 64; pb[i] += 64; }
    __syncthreads();
    #pragma unroll
    for(int kk = 0; kk < 2; ++kk){
      int xs = kk ? xs1 : xs0;
      s16x8 aF[4], bF[4];
      #pragma unroll
      for(int i = 0; i < 4; ++i){
        aF[i] = *(const s16x8*)&As[(wr*64 + i*16 + lrow)*64 + xs];
        bF[i] = *(const s16x8*)&Bs[(wc*64 + i*16 + lrow)*64 + xs];
      }
      #pragma unroll
      for(int i = 0; i < 4; ++i)
        #pragma unroll
        for(int jn = 0; jn < 4; ++jn)
          acc[i][jn] = mfma32(aF[i], bF[jn], acc[i][jn]);
    }
    __syncthreads();
  }

  u16* Oz = (u16*)O + zsO*(size_t)z;
  int zb = z*zoffmul;
  #pragma unroll
  for(int i = 0; i < 4; ++i){
    #pragma unroll
    for(int r = 0; r < 4; ++r){
      int row = m0 + wr*64 + i*16 + g4*4 + r;
      if(row >= M) continue;
      #pragma unroll
      for(int jn = 0; jn < 4; ++jn){
        int col = n0 + wc*64 + jn*16 + lrow;
        float v = acc[i][jn][r];
        if constexpr (EPI == 0){
          Oz[(size_t)row*N + col] = f2bf(v);
        } else if constexpr (EPI == 1){
          float u = v*(0.7978845608f + 0.0356774081f*v*v);
          float t = 1.f - 2.f/(__expf(2.f*u) + 1.f);
          Oz[(size_t)row*N + col] = f2bf(0.5f*v*(1.f + t));
        } else {
          int bi = row / TPB, nnn = row - bi*TPB;
          size_t cat = (size_t)bi*387 + zb + nnn;
          float* dst = (float*)O + cat*CC + col;
          if constexpr (KS > 1) atomicAdd(dst, v);
          else *dst += v;
        }
      }
    }
  }
}

// ---------------- attention v4: 128 q-rows/block (2 q-tiles per wave), K/V staged once ----------------
template<int N_>
__global__ __launch_bounds__(256) void attn3(
    const u16* __restrict__ qkv, size_t zsQ,
    u16* __restrict__ out, size_t zsO,
    const float* __restrict__ mask)
{
  constexpr int NC  = (N_ + 63)/64;
  constexpr int NKC = NC*64;
  constexpr float SCL = 0.125f*1.44269504088896f;
  __shared__ u16 Ks[2][64][66];
  __shared__ u16 Vt[2][64][68];
  __shared__ float Msk[NKC];

  int z = blockIdx.z;
  int bh = blockIdx.y, b = bh / HH, hh = bh - b*HH;
  int tid = threadIdx.x, wid = tid >> 6, lane = tid & 63;
  int lq = lane & 15, g = lane >> 4;
  const u16* qz = qkv + zsQ*(size_t)z;
  const size_t rowbase = (size_t)b*N_;
  const u16* kbase = qz + rowbase*2304 + 768 + hh*64;
  const u16* vbase = kbase + 768;

  for(int k = tid; k < NKC; k += 256){
    float mk = 0.f;
    if(k < N_){ int nn = (N_ > 129) ? (k % 129) : k; mk = (nn == 0) ? 1.f : mask[b*128 + nn - 1]; }
    Msk[k] = (mk != 0.f) ? 0.f : -1e30f;
  }

  int q0[2]; s16x8 qF0[2], qF1[2];
  #pragma unroll
  for(int qi = 0; qi < 2; ++qi){
    q0[qi] = blockIdx.x*128 + qi*64 + wid*16;
    int qrow = q0[qi] + lq;
    int qrc = qrow < N_ ? qrow : N_ - 1;
    const u16* qptr = qz + (rowbase + qrc)*2304 + hh*64;
    qF0[qi] = *(const s16x8*)(qptr + g*8);
    qF1[qi] = *(const s16x8*)(qptr + 32 + g*8);
  }

  int r0 = tid >> 3, c16 = tid & 7;
  s16x8 kr[2], vr[2];
  const s16x8 zv = {0,0,0,0,0,0,0,0};

  #pragma unroll
  for(int i = 0; i < 2; ++i){
    int row = r0 + i*32;
    kr[i] = (row < N_) ? *(const s16x8*)(kbase + (size_t)row*2304 + c16*8) : zv;
    vr[i] = (row < N_) ? *(const s16x8*)(vbase + (size_t)row*2304 + c16*8) : zv;
  }
  #pragma unroll
  for(int i = 0; i < 2; ++i){
    *(s16x8*)&Ks[0][r0 + i*32][c16*8] = kr[i];
    #pragma unroll
    for(int j = 0; j < 8; ++j) Vt[0][c16*8 + j][r0 + i*32] = (u16)vr[i][j];
  }
  __syncthreads();

  f32x4 o[2][4] = {};
  float l[2] = {0.f, 0.f};

  for(int ch = 0; ch < NC; ++ch){
    int cur = ch & 1;
    if(ch + 1 < NC){
      #pragma unroll
      for(int i = 0; i < 2; ++i){
        int row = (ch + 1)*64 + r0 + i*32;
        kr[i] = (row < N_) ? *(const s16x8*)(kbase + (size_t)row*2304 + c16*8) : zv;
        vr[i] = (row < N_) ? *(const s16x8*)(vbase + (size_t)row*2304 + c16*8) : zv;
      }
    }
    #pragma unroll
    for(int qi = 0; qi < 2; ++qi){
      float pT[4][4];
      #pragma unroll
      for(int t = 0; t < 4; ++t){
        s16x8 kF0 = *(const s16x8*)&Ks[cur][t*16 + lq][g*8];
        s16x8 kF1 = *(const s16x8*)&Ks[cur][t*16 + lq][32 + g*8];
        f32x4 s = {0.f,0.f,0.f,0.f};
        s = mfma32(kF0, qF0[qi], s);
        s = mfma32(kF1, qF1[qi], s);
        const float* mrow = &Msk[ch*64 + t*16 + g*4];
        #pragma unroll
        for(int r = 0; r < 4; ++r){
          float p = exp2f(fmaf(s[r], SCL, mrow[r]));
          pT[t][r] = p;
          l[qi] += p;
        }
      }
      #pragma unroll
      for(int t = 0; t < 4; ++t){
        s16x4 pa;
        #pragma unroll
        for(int r = 0; r < 4; ++r) pa[r] = (short)f2bf(pT[t][r]);
        #pragma unroll
        for(int db = 0; db < 4; ++db){
          s16x4 vf = *(const s16x4*)&Vt[cur][db*16 + lq][t*16 + g*4];
          o[qi][db] = mfma16(pa, vf, o[qi][db]);
        }
      }
    }
    if(ch + 1 < NC){
      int nxt = (ch + 1) & 1;
      #pragma unroll
      for(int i = 0; i < 2; ++i){
        *(s16x8*)&Ks[nxt][r0 + i*32][c16*8] = kr[i];
        #pragma unroll
        for(int j = 0; j < 8; ++j) Vt[nxt][c16*8 + j][r0 + i*32] = (u16)vr[i][j];
      }
      __syncthreads();
    }
  }

  #pragma unroll
  for(int qi = 0; qi < 2; ++qi){
    float lv = l[qi];
    lv += __shfl_xor(lv, 16);
    lv += __shfl_xor(lv, 32);
    int qrow = q0[qi] + lq;
    float mq = 0.f;
    if(qrow < N_) mq = (Msk[qrow] == 0.f) ? 1.f : 0.f;
    float sc = mq / lv;
    float scr[4];
    #pragma unroll
    for(int r = 0; r < 4; ++r) scr[r] = __shfl(sc, g*4 + r);
    #pragma unroll
    for(int db = 0; db < 4; ++db){
      #pragma unroll
      for(int r = 0; r < 4; ++r){
        int qq = q0[qi] + g*4 + r;
        if(qq < N_)
          out[zsO*(size_t)z + (rowbase + qq)*CC + hh*64 + db*16 + lq] = f2bf(o[qi][db][r]*scr[r]);
      }
    }
  }
}

extern "C" void kernel_launch(void* const* d_in, const int* in_sizes, int n_in,
                              void* d_out, int out_size, void* d_ws, size_t ws_size,
                              hipStream_t stream)
{
  const float* RGB   = (const float*)d_in[0];
  const float* NIR   = (const float*)d_in[1];
  const float* TIR   = (const float*)d_in[2];
  const float* mask  = (const float*)d_in[3];
  const float* ln_g1 = (const float*)d_in[5];
  const float* ln_b1 = (const float*)d_in[6];
  const float* w_qkv = (const float*)d_in[7];
  const float* w_proj= (const float*)d_in[8];
  const float* ln_g2 = (const float*)d_in[9];
  const float* ln_b2 = (const float*)d_in[10];
  const float* w_fc1 = (const float*)d_in[11];
  const float* w_fc2 = (const float*)d_in[12];
  const float* out_g = (const float*)d_in[13];
  const float* out_b = (const float*)d_in[14];

  char* p = (char*)d_ws;
  u16* wqkv_t  = (u16*)p; p += (size_t)4*2304*768*2;
  u16* wproj_t = (u16*)p; p += (size_t)4*768*768*2;
  u16* w1_t    = (u16*)p; p += (size_t)4*768*3072*2;
  u16* w2_t    = (u16*)p; p += (size_t)4*3072*768*2;
  float* xcat  = (float*)p; p += (size_t)12384*768*4;
  u16* xm      = (u16*)p; p += (size_t)3*4224*768*2;
  u16* qkv     = (u16*)p; p += (size_t)3*4224*3072*2;
  u16* hbuf    = qkv;
  if((size_t)(p - (char*)d_ws) > ws_size) return;

  wtrans<<<dim3(24, 72, 4), 256, 0, stream>>>(w_qkv, wqkv_t, 768, 2304);
  wtrans<<<dim3(24, 24, 4), 256, 0, stream>>>(w_proj, wproj_t, 768, 768);
  wtrans<<<dim3(24, 96, 4), 256, 0, stream>>>(w_fc1, w1_t, 768, 3072);
  wtrans<<<dim3(96, 24, 4), 256, 0, stream>>>(w_fc2, w2_t, 3072, 768);
  initcat<<<dim3(3096, 3), 256, 0, stream>>>(RGB, NIR, TIR, xcat);

  const int M3 = 4128;
  const size_t zxm = (size_t)4224*768, zqkv = (size_t)4224*2304, zh = (size_t)4224*3072;
  // ---- branches 0..2 ----
  ln_mask<0><<<dim3(M3/4,3), 256, 0, stream>>>(xcat, ln_g1, ln_b1, 768, mask, xm, zxm, 129, 129);
  gemm_bt<0,1,1><<<dim3(33,18,3), 256, 0, stream>>>(xm, zxm, wqkv_t, (size_t)2304*768, qkv, zqkv, M3, 2304, 768, 0);
  attn3<129><<<dim3(2,384,3), 256, 0, stream>>>(qkv, zqkv, xm, zxm, mask);
  gemm_bt<2,129,2><<<dim3(33,6,6), 256, 0, stream>>>(xm, zxm, wproj_t, (size_t)768*768, xcat, 0, M3, 768, 768, 129);
  ln_mask<0><<<dim3(M3/4,3), 256, 0, stream>>>(xcat, ln_g2, ln_b2, 768, mask, xm, zxm, 129, 129);
  gemm_bt<1,1,1><<<dim3(33,24,3), 256, 0, stream>>>(xm, zxm, w1_t, (size_t)768*3072, hbuf, zh, M3, 3072, 768, 0);
  gemm_bt<2,129,2><<<dim3(33,6,6), 256, 0, stream>>>(hbuf, zh, w2_t, (size_t)768*3072, xcat, 0, M3, 768, 3072, 129);
  // ---- concat branch ----
  const int M1 = 12384;
  ln_mask<0><<<dim3(M1/4,1), 256, 0, stream>>>(xcat, ln_g1 + 3*768, ln_b1 + 3*768, 0, mask, xm, 0, 387, 0);
  gemm_bt<0,1,1><<<dim3(97,18,1), 256, 0, stream>>>(xm, 0, wqkv_t + (size_t)3*2304*768, 0, qkv, 0, M1, 2304, 768, 0);
  attn3<387><<<dim3(4,384,1), 256, 0, stream>>>(qkv, 0, xm, 0, mask);
  gemm_bt<2,387,2><<<dim3(97,6,2), 256, 0, stream>>>(xm, 0, wproj_t + (size_t)3*768*768, 0, xcat, 0, M1, 768, 768, 0);
  ln_mask<0><<<dim3(M1/4,1), 256, 0, stream>>>(xcat, ln_g2 + 3*768, ln_b2 + 3*768, 0, mask, xm, 0, 387, 0);
  gemm_bt<1,1,1><<<dim3(97,24,1), 256, 0, stream>>>(xm, 0, w1_t + (size_t)3*768*3072, 0, hbuf, 0, M1, 3072, 768, 0);
  gemm_bt<2,387,2><<<dim3(97,6,2), 256, 0, stream>>>(hbuf, 0, w2_t + (size_t)3*768*3072, 0, xcat, 0, M1, 768, 3072, 0);
  // ---- final LN ----
  ln_mask<1><<<dim3(M1/4,1), 256, 0, stream>>>(xcat, out_g, out_b, 0, mask, d_out, 0, 387, 0);
}

// Round 15
// 837.415 us; speedup vs baseline: 1.7012x; 1.7012x over previous
//
#include <hip/hip_runtime.h>

typedef unsigned short u16;
typedef __attribute__((ext_vector_type(4))) float f32x4;
typedef __attribute__((ext_vector_type(8))) short s16x8;
typedef __attribute__((ext_vector_type(4))) short s16x4;
typedef __attribute__((ext_vector_type(4))) unsigned short u16x4;

#define HH 12
#define CC 768
#define AS1(p) ((const __attribute__((address_space(1))) void*)(p))
#define AS3(p) ((__attribute__((address_space(3))) void*)(p))

__device__ inline u16 f2bf(float x){
  unsigned u = __float_as_uint(x);
  u = (u + 0x7FFFu + ((u >> 16) & 1u)) >> 16;
  return (u16)u;
}

__device__ inline f32x4 mfma32(s16x8 a, s16x8 b, f32x4 c){
  return __builtin_amdgcn_mfma_f32_16x16x32_bf16(a, b, c, 0, 0, 0);
}
__device__ inline f32x4 mfma16(s16x4 a, s16x4 b, f32x4 c){
  return __builtin_amdgcn_mfma_f32_16x16x16bf16_1k(a, b, c, 0, 0, 0);
}

__device__ inline void xcd_remap(int gx, int gy, int& bx, int& by){
  int nwg = gx*gy;
  int orig = blockIdx.x + gx*blockIdx.y;
  int q = nwg >> 3, r8 = nwg & 7;
  int xcd = orig & 7, off = orig >> 3;
  int wg = (xcd < r8 ? xcd*(q+1) : r8*(q+1) + (xcd-r8)*q) + off;
  bx = wg / gy; by = wg - bx*gy;
}

// ---------------- weight fp32 [K,N] -> bf16 [N,K] (per blockIdx.z set) ----------------
__global__ void wtrans(const float* __restrict__ W, u16* __restrict__ Wt, int K, int N){
  __shared__ float tile[32][33];
  int k0 = blockIdx.x*32, n0 = blockIdx.y*32;
  const float* Wz = W + (size_t)blockIdx.z*K*N;
  u16* Wtz = Wt + (size_t)blockIdx.z*K*N;
  int tx = threadIdx.x & 31, ty = threadIdx.x >> 5;
  #pragma unroll
  for(int r = ty; r < 32; r += 8)
    tile[r][tx] = Wz[(size_t)(k0+r)*N + n0 + tx];
  __syncthreads();
  #pragma unroll
  for(int r = ty; r < 32; r += 8)
    Wtz[(size_t)(n0+r)*K + k0 + tx] = f2bf(tile[tx][r]);
}

// ---------------- scatter RGB/NIR/TIR into concat layout [B,387,C] ----------------
__global__ void initcat(const float* __restrict__ R, const float* __restrict__ Nr,
                        const float* __restrict__ T, float* __restrict__ xcat){
  int idx = blockIdx.x*256 + threadIdx.x;
  const int per = 32*129*768/4;
  if(idx >= per) return;
  int z = blockIdx.y;
  const float* src = z == 0 ? R : (z == 1 ? Nr : T);
  float4 v = ((const float4*)src)[idx];
  int e = idx*4;
  int row = e / 768, c = e - row*768;
  int bb2 = row / 129, nn = row - bb2*129;
  ((float4*)xcat)[((size_t)(bb2*387 + z*129 + nn)*768 + c)/4] = v;
}

__device__ inline float maskval(const float* m, int b, int n){
  return (n == 0) ? 1.0f : m[b*128 + n - 1];
}

// ---------------- LayerNorm * mask : 4 rows per 256-thr block ----------------
template<int F32OUT>
__global__ __launch_bounds__(256) void ln_mask(
    const float* __restrict__ x,
    const float* __restrict__ gg, const float* __restrict__ bb, int zsG,
    const float* __restrict__ mask,
    void* __restrict__ out, size_t zsO,
    int tpb, int zoffmul)
{
  int wid = threadIdx.x >> 6, lane = threadIdx.x & 63;
  int r = blockIdx.x*4 + wid, z = blockIdx.y;
  int bidx = r / tpb, nn = r - bidx*tpb;
  size_t cat = (size_t)bidx*387 + z*zoffmul + nn;
  const float4* xr = (const float4*)(x + cat*CC);
  float4 v[3]; float s = 0.f, sq = 0.f;
  #pragma unroll
  for(int w = 0; w < 3; ++w){
    v[w] = xr[w*64 + lane];
    s  += v[w].x + v[w].y + v[w].z + v[w].w;
    sq += v[w].x*v[w].x + v[w].y*v[w].y + v[w].z*v[w].z + v[w].w*v[w].w;
  }
  #pragma unroll
  for(int o = 32; o; o >>= 1){ s += __shfl_xor(s, o); sq += __shfl_xor(sq, o); }
  float mu = s * (1.f/768.f);
  float var = sq * (1.f/768.f) - mu*mu;
  float rstd = rsqrtf(var + 1e-5f);
  float mv = maskval(mask, bidx, nn % 129);
  const float4* g4 = (const float4*)(gg + (size_t)z*zsG);
  const float4* b4 = (const float4*)(bb + (size_t)z*zsG);
  #pragma unroll
  for(int w = 0; w < 3; ++w){
    float4 gv = g4[w*64+lane], bv = b4[w*64+lane];
    float y0 = ((v[w].x - mu)*rstd*gv.x + bv.x) * mv;
    float y1 = ((v[w].y - mu)*rstd*gv.y + bv.y) * mv;
    float y2 = ((v[w].z - mu)*rstd*gv.z + bv.z) * mv;
    float y3 = ((v[w].w - mu)*rstd*gv.w + bv.w) * mv;
    if(F32OUT){
      ((float4*)out)[cat*(CC/4) + w*64 + lane] = make_float4(y0,y1,y2,y3);
    } else {
      u16x4 p; p.x = f2bf(y0); p.y = f2bf(y1); p.z = f2bf(y2); p.w = f2bf(y3);
      ((u16x4*)((u16*)out + z*zsO + (size_t)r*CC))[w*64 + lane] = p;
    }
  }
}

// ---------------- GEMM 128x128 (single-buf BK=64, swizzle, high TLP; optional split-K) ----------------
// EPI 0: bf16 store ; 1: tanh-gelu bf16 ; 2: residual-add fp32 xcat (atomic when KS>1)
// launch_bounds (256,4): VGPR cap 128 -> no spill (acc needs 64+). (256,5) spilled, r14.
template<int EPI, int TPB, int KS>
__global__ __launch_bounds__(256, 4) void gemm_bt(
    const u16* __restrict__ A, size_t zsA,
    const u16* __restrict__ Bt, size_t zsB,
    void* __restrict__ O, size_t zsO,
    int M, int N, int K,
    int zoffmul)
{
  __shared__ u16 As[128*64];
  __shared__ u16 Bs[128*64];
  int bz = blockIdx.z;
  int z = bz / KS, ks = bz - z*KS;
  int KSL = K / KS;
  const u16* Az = A + zsA*(size_t)z + ks*KSL;
  const u16* Bz = Bt + zsB*(size_t)z + ks*KSL;
  int bx, by; xcd_remap(gridDim.x, gridDim.y, bx, by);
  int m0 = bx*128, n0 = by*128;

  int tid = threadIdx.x, wid = tid >> 6, lane = tid & 63;
  int wr = wid >> 1, wc = wid & 1;
  int lrow = lane & 15, g4 = lane >> 4;

  int srow = tid >> 3;
  int swcol = ((tid & 7) ^ (srow & 7)) * 8;
  const u16 *pa[4], *pb[4];
  #pragma unroll
  for(int i = 0; i < 4; ++i){
    int ra = m0 + srow + i*32; ra = ra < M ? ra : M - 1;
    pa[i] = Az + (size_t)ra*K + swcol;
    pb[i] = Bz + (size_t)(n0 + srow + i*32)*K + swcol;
  }
  int dofs = tid*8;
  int xs0 = ((0*4 + g4) ^ (lrow & 7)) * 8;
  int xs1 = ((1*4 + g4) ^ (lrow & 7)) * 8;

  f32x4 acc[4][4] = {};
  int NT = KSL >> 6;

  for(int t = 0; t < NT; ++t){
    #pragma unroll
    for(int i = 0; i < 4; ++i)
      __builtin_amdgcn_global_load_lds(AS1(pa[i]), AS3(&As[dofs + i*2048]), 16, 0, 0);
    #pragma unroll
    for(int i = 0; i < 4; ++i)
      __builtin_amdgcn_global_load_lds(AS1(pb[i]), AS3(&Bs[dofs + i*2048]), 16, 0, 0);
    #pragma unroll
    for(int i = 0; i < 4; ++i){ pa[i] += 64; pb[i] += 64; }
    __syncthreads();
    #pragma unroll
    for(int kk = 0; kk < 2; ++kk){
      int xs = kk ? xs1 : xs0;
      s16x8 aF[4], bF[4];
      #pragma unroll
      for(int i = 0; i < 4; ++i){
        aF[i] = *(const s16x8*)&As[(wr*64 + i*16 + lrow)*64 + xs];
        bF[i] = *(const s16x8*)&Bs[(wc*64 + i*16 + lrow)*64 + xs];
      }
      #pragma unroll
      for(int i = 0; i < 4; ++i)
        #pragma unroll
        for(int jn = 0; jn < 4; ++jn)
          acc[i][jn] = mfma32(aF[i], bF[jn], acc[i][jn]);
    }
    __syncthreads();
  }

  u16* Oz = (u16*)O + zsO*(size_t)z;
  int zb = z*zoffmul;
  #pragma unroll
  for(int i = 0; i < 4; ++i){
    #pragma unroll
    for(int r = 0; r < 4; ++r){
      int row = m0 + wr*64 + i*16 + g4*4 + r;
      if(row >= M) continue;
      #pragma unroll
      for(int jn = 0; jn < 4; ++jn){
        int col = n0 + wc*64 + jn*16 + lrow;
        float v = acc[i][jn][r];
        if constexpr (EPI == 0){
          Oz[(size_t)row*N + col] = f2bf(v);
        } else if constexpr (EPI == 1){
          float u = v*(0.7978845608f + 0.0356774081f*v*v);
          float t = 1.f - 2.f/(__expf(2.f*u) + 1.f);
          Oz[(size_t)row*N + col] = f2bf(0.5f*v*(1.f + t));
        } else {
          int bi = row / TPB, nnn = row - bi*TPB;
          size_t cat = (size_t)bi*387 + zb + nnn;
          float* dst = (float*)O + cat*CC + col;
          if constexpr (KS > 1) atomicAdd(dst, v);
          else *dst += v;
        }
      }
    }
  }
}

// ---------------- attention v4: 128 q-rows/block (2 q-tiles per wave), K/V staged once ----------------
template<int N_>
__global__ __launch_bounds__(256) void attn3(
    const u16* __restrict__ qkv, size_t zsQ,
    u16* __restrict__ out, size_t zsO,
    const float* __restrict__ mask)
{
  constexpr int NC  = (N_ + 63)/64;
  constexpr int NKC = NC*64;
  constexpr float SCL = 0.125f*1.44269504088896f;
  __shared__ u16 Ks[2][64][66];
  __shared__ u16 Vt[2][64][68];
  __shared__ float Msk[NKC];

  int z = blockIdx.z;
  int bh = blockIdx.y, b = bh / HH, hh = bh - b*HH;
  int tid = threadIdx.x, wid = tid >> 6, lane = tid & 63;
  int lq = lane & 15, g = lane >> 4;
  const u16* qz = qkv + zsQ*(size_t)z;
  const size_t rowbase = (size_t)b*N_;
  const u16* kbase = qz + rowbase*2304 + 768 + hh*64;
  const u16* vbase = kbase + 768;

  for(int k = tid; k < NKC; k += 256){
    float mk = 0.f;
    if(k < N_){ int nn = (N_ > 129) ? (k % 129) : k; mk = (nn == 0) ? 1.f : mask[b*128 + nn - 1]; }
    Msk[k] = (mk != 0.f) ? 0.f : -1e30f;
  }

  int q0[2]; s16x8 qF0[2], qF1[2];
  #pragma unroll
  for(int qi = 0; qi < 2; ++qi){
    q0[qi] = blockIdx.x*128 + qi*64 + wid*16;
    int qrow = q0[qi] + lq;
    int qrc = qrow < N_ ? qrow : N_ - 1;
    const u16* qptr = qz + (rowbase + qrc)*2304 + hh*64;
    qF0[qi] = *(const s16x8*)(qptr + g*8);
    qF1[qi] = *(const s16x8*)(qptr + 32 + g*8);
  }

  int r0 = tid >> 3, c16 = tid & 7;
  s16x8 kr[2], vr[2];
  const s16x8 zv = {0,0,0,0,0,0,0,0};

  #pragma unroll
  for(int i = 0; i < 2; ++i){
    int row = r0 + i*32;
    kr[i] = (row < N_) ? *(const s16x8*)(kbase + (size_t)row*2304 + c16*8) : zv;
    vr[i] = (row < N_) ? *(const s16x8*)(vbase + (size_t)row*2304 + c16*8) : zv;
  }
  #pragma unroll
  for(int i = 0; i < 2; ++i){
    *(s16x8*)&Ks[0][r0 + i*32][c16*8] = kr[i];
    #pragma unroll
    for(int j = 0; j < 8; ++j) Vt[0][c16*8 + j][r0 + i*32] = (u16)vr[i][j];
  }
  __syncthreads();

  f32x4 o[2][4] = {};
  float l[2] = {0.f, 0.f};

  for(int ch = 0; ch < NC; ++ch){
    int cur = ch & 1;
    if(ch + 1 < NC){
      #pragma unroll
      for(int i = 0; i < 2; ++i){
        int row = (ch + 1)*64 + r0 + i*32;
        kr[i] = (row < N_) ? *(const s16x8*)(kbase + (size_t)row*2304 + c16*8) : zv;
        vr[i] = (row < N_) ? *(const s16x8*)(vbase + (size_t)row*2304 + c16*8) : zv;
      }
    }
    #pragma unroll
    for(int qi = 0; qi < 2; ++qi){
      float pT[4][4];
      #pragma unroll
      for(int t = 0; t < 4; ++t){
        s16x8 kF0 = *(const s16x8*)&Ks[cur][t*16 + lq][g*8];
        s16x8 kF1 = *(const s16x8*)&Ks[cur][t*16 + lq][32 + g*8];
        f32x4 s = {0.f,0.f,0.f,0.f};
        s = mfma32(kF0, qF0[qi], s);
        s = mfma32(kF1, qF1[qi], s);
        const float* mrow = &Msk[ch*64 + t*16 + g*4];
        #pragma unroll
        for(int r = 0; r < 4; ++r){
          float p = exp2f(fmaf(s[r], SCL, mrow[r]));
          pT[t][r] = p;
          l[qi] += p;
        }
      }
      #pragma unroll
      for(int t = 0; t < 4; ++t){
        s16x4 pa;
        #pragma unroll
        for(int r = 0; r < 4; ++r) pa[r] = (short)f2bf(pT[t][r]);
        #pragma unroll
        for(int db = 0; db < 4; ++db){
          s16x4 vf = *(const s16x4*)&Vt[cur][db*16 + lq][t*16 + g*4];
          o[qi][db] = mfma16(pa, vf, o[qi][db]);
        }
      }
    }
    if(ch + 1 < NC){
      int nxt = (ch + 1) & 1;
      #pragma unroll
      for(int i = 0; i < 2; ++i){
        *(s16x8*)&Ks[nxt][r0 + i*32][c16*8] = kr[i];
        #pragma unroll
        for(int j = 0; j < 8; ++j) Vt[nxt][c16*8 + j][r0 + i*32] = (u16)vr[i][j];
      }
      __syncthreads();
    }
  }

  #pragma unroll
  for(int qi = 0; qi < 2; ++qi){
    float lv = l[qi];
    lv += __shfl_xor(lv, 16);
    lv += __shfl_xor(lv, 32);
    int qrow = q0[qi] + lq;
    float mq = 0.f;
    if(qrow < N_) mq = (Msk[qrow] == 0.f) ? 1.f : 0.f;
    float sc = mq / lv;
    float scr[4];
    #pragma unroll
    for(int r = 0; r < 4; ++r) scr[r] = __shfl(sc, g*4 + r);
    #pragma unroll
    for(int db = 0; db < 4; ++db){
      #pragma unroll
      for(int r = 0; r < 4; ++r){
        int qq = q0[qi] + g*4 + r;
        if(qq < N_)
          out[zsO*(size_t)z + (rowbase + qq)*CC + hh*64 + db*16 + lq] = f2bf(o[qi][db][r]*scr[r]);
      }
    }
  }
}

extern "C" void kernel_launch(void* const* d_in, const int* in_sizes, int n_in,
                              void* d_out, int out_size, void* d_ws, size_t ws_size,
                              hipStream_t stream)
{
  const float* RGB   = (const float*)d_in[0];
  const float* NIR   = (const float*)d_in[1];
  const float* TIR   = (const float*)d_in[2];
  const float* mask  = (const float*)d_in[3];
  const float* ln_g1 = (const float*)d_in[5];
  const float* ln_b1 = (const float*)d_in[6];
  const float* w_qkv = (const float*)d_in[7];
  const float* w_proj= (const float*)d_in[8];
  const float* ln_g2 = (const float*)d_in[9];
  const float* ln_b2 = (const float*)d_in[10];
  const float* w_fc1 = (const float*)d_in[11];
  const float* w_fc2 = (const float*)d_in[12];
  const float* out_g = (const float*)d_in[13];
  const float* out_b = (const float*)d_in[14];

  char* p = (char*)d_ws;
  u16* wqkv_t  = (u16*)p; p += (size_t)4*2304*768*2;
  u16* wproj_t = (u16*)p; p += (size_t)4*768*768*2;
  u16* w1_t    = (u16*)p; p += (size_t)4*768*3072*2;
  u16* w2_t    = (u16*)p; p += (size_t)4*3072*768*2;
  float* xcat  = (float*)p; p += (size_t)12384*768*4;
  u16* xm      = (u16*)p; p += (size_t)3*4224*768*2;
  u16* qkv     = (u16*)p; p += (size_t)3*4224*3072*2;
  u16* hbuf    = qkv;
  if((size_t)(p - (char*)d_ws) > ws_size) return;

  wtrans<<<dim3(24, 72, 4), 256, 0, stream>>>(w_qkv, wqkv_t, 768, 2304);
  wtrans<<<dim3(24, 24, 4), 256, 0, stream>>>(w_proj, wproj_t, 768, 768);
  wtrans<<<dim3(24, 96, 4), 256, 0, stream>>>(w_fc1, w1_t, 768, 3072);
  wtrans<<<dim3(96, 24, 4), 256, 0, stream>>>(w_fc2, w2_t, 3072, 768);
  initcat<<<dim3(3096, 3), 256, 0, stream>>>(RGB, NIR, TIR, xcat);

  const int M3 = 4128;
  const size_t zxm = (size_t)4224*768, zqkv = (size_t)4224*2304, zh = (size_t)4224*3072;
  // ---- branches 0..2 ----
  ln_mask<0><<<dim3(M3/4,3), 256, 0, stream>>>(xcat, ln_g1, ln_b1, 768, mask, xm, zxm, 129, 129);
  gemm_bt<0,1,1><<<dim3(33,18,3), 256, 0, stream>>>(xm, zxm, wqkv_t, (size_t)2304*768, qkv, zqkv, M3, 2304, 768, 0);
  attn3<129><<<dim3(2,384,3), 256, 0, stream>>>(qkv, zqkv, xm, zxm, mask);
  gemm_bt<2,129,2><<<dim3(33,6,6), 256, 0, stream>>>(xm, zxm, wproj_t, (size_t)768*768, xcat, 0, M3, 768, 768, 129);
  ln_mask<0><<<dim3(M3/4,3), 256, 0, stream>>>(xcat, ln_g2, ln_b2, 768, mask, xm, zxm, 129, 129);
  gemm_bt<1,1,1><<<dim3(33,24,3), 256, 0, stream>>>(xm, zxm, w1_t, (size_t)768*3072, hbuf, zh, M3, 3072, 768, 0);
  gemm_bt<2,129,2><<<dim3(33,6,6), 256, 0, stream>>>(hbuf, zh, w2_t, (size_t)768*3072, xcat, 0, M3, 768, 3072, 129);
  // ---- concat branch ----
  const int M1 = 12384;
  ln_mask<0><<<dim3(M1/4,1), 256, 0, stream>>>(xcat, ln_g1 + 3*768, ln_b1 + 3*768, 0, mask, xm, 0, 387, 0);
  gemm_bt<0,1,1><<<dim3(97,18,1), 256, 0, stream>>>(xm, 0, wqkv_t + (size_t)3*2304*768, 0, qkv, 0, M1, 2304, 768, 0);
  attn3<387><<<dim3(4,384,1), 256, 0, stream>>>(qkv, 0, xm, 0, mask);
  gemm_bt<2,387,2><<<dim3(97,6,2), 256, 0, stream>>>(xm, 0, wproj_t + (size_t)3*768*768, 0, xcat, 0, M1, 768, 768, 0);
  ln_mask<0><<<dim3(M1/4,1), 256, 0, stream>>>(xcat, ln_g2 + 3*768, ln_b2 + 3*768, 0, mask, xm, 0, 387, 0);
  gemm_bt<1,1,1><<<dim3(97,24,1), 256, 0, stream>>>(xm, 0, w1_t + (size_t)3*768*3072, 0, hbuf, 0, M1, 3072, 768, 0);
  gemm_bt<2,387,2><<<dim3(97,6,2), 256, 0, stream>>>(hbuf, 0, w2_t + (size_t)3*768*3072, 0, xcat, 0, M1, 768, 3072, 0);
  // ---- final LN ----
  ln_mask<1><<<dim3(M1/4,1), 256, 0, stream>>>(xcat, out_g, out_b, 0, mask, d_out, 0, 387, 0);
}

// Round 16
// 826.717 us; speedup vs baseline: 1.7232x; 1.0129x over previous
//
#include <hip/hip_runtime.h>

typedef unsigned short u16;
typedef __attribute__((ext_vector_type(4))) float f32x4;
typedef __attribute__((ext_vector_type(8))) short s16x8;
typedef __attribute__((ext_vector_type(4))) short s16x4;
typedef __attribute__((ext_vector_type(4))) unsigned short u16x4;

#define HH 12
#define CC 768
#define AS1(p) ((const __attribute__((address_space(1))) void*)(p))
#define AS3(p) ((__attribute__((address_space(3))) void*)(p))

__device__ inline u16 f2bf(float x){
  unsigned u = __float_as_uint(x);
  u = (u + 0x7FFFu + ((u >> 16) & 1u)) >> 16;
  return (u16)u;
}

__device__ inline f32x4 mfma32(s16x8 a, s16x8 b, f32x4 c){
  return __builtin_amdgcn_mfma_f32_16x16x32_bf16(a, b, c, 0, 0, 0);
}
__device__ inline f32x4 mfma16(s16x4 a, s16x4 b, f32x4 c){
  return __builtin_amdgcn_mfma_f32_16x16x16bf16_1k(a, b, c, 0, 0, 0);
}

__device__ inline void xcd_remap(int gx, int gy, int& bx, int& by){
  int nwg = gx*gy;
  int orig = blockIdx.x + gx*blockIdx.y;
  int q = nwg >> 3, r8 = nwg & 7;
  int xcd = orig & 7, off = orig >> 3;
  int wg = (xcd < r8 ? xcd*(q+1) : r8*(q+1) + (xcd-r8)*q) + off;
  bx = wg / gy; by = wg - bx*gy;
}

// ---------------- weight fp32 [K,N] -> bf16 [N,K] (per blockIdx.z set) ----------------
__global__ void wtrans(const float* __restrict__ W, u16* __restrict__ Wt, int K, int N){
  __shared__ float tile[32][33];
  int k0 = blockIdx.x*32, n0 = blockIdx.y*32;
  const float* Wz = W + (size_t)blockIdx.z*K*N;
  u16* Wtz = Wt + (size_t)blockIdx.z*K*N;
  int tx = threadIdx.x & 31, ty = threadIdx.x >> 5;
  #pragma unroll
  for(int r = ty; r < 32; r += 8)
    tile[r][tx] = Wz[(size_t)(k0+r)*N + n0 + tx];
  __syncthreads();
  #pragma unroll
  for(int r = ty; r < 32; r += 8)
    Wtz[(size_t)(n0+r)*K + k0 + tx] = f2bf(tile[tx][r]);
}

// ---------------- scatter RGB/NIR/TIR into concat layout [B,387,C] ----------------
__global__ void initcat(const float* __restrict__ R, const float* __restrict__ Nr,
                        const float* __restrict__ T, float* __restrict__ xcat){
  int idx = blockIdx.x*256 + threadIdx.x;
  const int per = 32*129*768/4;
  if(idx >= per) return;
  int z = blockIdx.y;
  const float* src = z == 0 ? R : (z == 1 ? Nr : T);
  float4 v = ((const float4*)src)[idx];
  int e = idx*4;
  int row = e / 768, c = e - row*768;
  int bb2 = row / 129, nn = row - bb2*129;
  ((float4*)xcat)[((size_t)(bb2*387 + z*129 + nn)*768 + c)/4] = v;
}

__device__ inline float maskval(const float* m, int b, int n){
  return (n == 0) ? 1.0f : m[b*128 + n - 1];
}

// ---------------- LayerNorm * mask : 4 rows per 256-thr block ----------------
template<int F32OUT>
__global__ __launch_bounds__(256) void ln_mask(
    const float* __restrict__ x,
    const float* __restrict__ gg, const float* __restrict__ bb, int zsG,
    const float* __restrict__ mask,
    void* __restrict__ out, size_t zsO,
    int tpb, int zoffmul)
{
  int wid = threadIdx.x >> 6, lane = threadIdx.x & 63;
  int r = blockIdx.x*4 + wid, z = blockIdx.y;
  int bidx = r / tpb, nn = r - bidx*tpb;
  size_t cat = (size_t)bidx*387 + z*zoffmul + nn;
  const float4* xr = (const float4*)(x + cat*CC);
  float4 v[3]; float s = 0.f, sq = 0.f;
  #pragma unroll
  for(int w = 0; w < 3; ++w){
    v[w] = xr[w*64 + lane];
    s  += v[w].x + v[w].y + v[w].z + v[w].w;
    sq += v[w].x*v[w].x + v[w].y*v[w].y + v[w].z*v[w].z + v[w].w*v[w].w;
  }
  #pragma unroll
  for(int o = 32; o; o >>= 1){ s += __shfl_xor(s, o); sq += __shfl_xor(sq, o); }
  float mu = s * (1.f/768.f);
  float var = sq * (1.f/768.f) - mu*mu;
  float rstd = rsqrtf(var + 1e-5f);
  float mv = maskval(mask, bidx, nn % 129);
  const float4* g4 = (const float4*)(gg + (size_t)z*zsG);
  const float4* b4 = (const float4*)(bb + (size_t)z*zsG);
  #pragma unroll
  for(int w = 0; w < 3; ++w){
    float4 gv = g4[w*64+lane], bv = b4[w*64+lane];
    float y0 = ((v[w].x - mu)*rstd*gv.x + bv.x) * mv;
    float y1 = ((v[w].y - mu)*rstd*gv.y + bv.y) * mv;
    float y2 = ((v[w].z - mu)*rstd*gv.z + bv.z) * mv;
    float y3 = ((v[w].w - mu)*rstd*gv.w + bv.w) * mv;
    if(F32OUT){
      ((float4*)out)[cat*(CC/4) + w*64 + lane] = make_float4(y0,y1,y2,y3);
    } else {
      u16x4 p; p.x = f2bf(y0); p.y = f2bf(y1); p.z = f2bf(y2); p.w = f2bf(y3);
      ((u16x4*)((u16*)out + z*zsO + (size_t)r*CC))[w*64 + lane] = p;
    }
  }
}

// ---------------- GEMM 128x128 (r13-verified) -- proj ----------------
template<int EPI, int TPB>
__global__ __launch_bounds__(256, 4) void gemm_bt(
    const u16* __restrict__ A, size_t zsA,
    const u16* __restrict__ Bt, size_t zsB,
    void* __restrict__ O, size_t zsO,
    int M, int N, int K,
    int zoffmul)
{
  __shared__ u16 As[128*64];
  __shared__ u16 Bs[128*64];
  int z = blockIdx.z;
  const u16* Az = A + zsA*(size_t)z;
  const u16* Bz = Bt + zsB*(size_t)z;
  int bx, by; xcd_remap(gridDim.x, gridDim.y, bx, by);
  int m0 = bx*128, n0 = by*128;

  int tid = threadIdx.x, wid = tid >> 6, lane = tid & 63;
  int wr = wid >> 1, wc = wid & 1;
  int lrow = lane & 15, g4 = lane >> 4;

  int srow = tid >> 3;
  int swcol = ((tid & 7) ^ (srow & 7)) * 8;
  const u16 *pa[4], *pb[4];
  #pragma unroll
  for(int i = 0; i < 4; ++i){
    int ra = m0 + srow + i*32; ra = ra < M ? ra : M - 1;
    pa[i] = Az + (size_t)ra*K + swcol;
    pb[i] = Bz + (size_t)(n0 + srow + i*32)*K + swcol;
  }
  int dofs = tid*8;
  int xs0 = ((0*4 + g4) ^ (lrow & 7)) * 8;
  int xs1 = ((1*4 + g4) ^ (lrow & 7)) * 8;

  f32x4 acc[4][4] = {};
  int NT = K >> 6;

  for(int t = 0; t < NT; ++t){
    #pragma unroll
    for(int i = 0; i < 4; ++i)
      __builtin_amdgcn_global_load_lds(AS1(pa[i]), AS3(&As[dofs + i*2048]), 16, 0, 0);
    #pragma unroll
    for(int i = 0; i < 4; ++i)
      __builtin_amdgcn_global_load_lds(AS1(pb[i]), AS3(&Bs[dofs + i*2048]), 16, 0, 0);
    #pragma unroll
    for(int i = 0; i < 4; ++i){ pa[i] += 64; pb[i] += 64; }
    __syncthreads();
    #pragma unroll
    for(int kk = 0; kk < 2; ++kk){
      int xs = kk ? xs1 : xs0;
      s16x8 aF[4], bF[4];
      #pragma unroll
      for(int i = 0; i < 4; ++i){
        aF[i] = *(const s16x8*)&As[(wr*64 + i*16 + lrow)*64 + xs];
        bF[i] = *(const s16x8*)&Bs[(wc*64 + i*16 + lrow)*64 + xs];
      }
      #pragma unroll
      for(int i = 0; i < 4; ++i)
        #pragma unroll
        for(int jn = 0; jn < 4; ++jn)
          acc[i][jn] = mfma32(aF[i], bF[jn], acc[i][jn]);
    }
    __syncthreads();
  }

  u16* Oz = (u16*)O + zsO*(size_t)z;
  int zb = z*zoffmul;
  #pragma unroll
  for(int i = 0; i < 4; ++i){
    #pragma unroll
    for(int r = 0; r < 4; ++r){
      int row = m0 + wr*64 + i*16 + g4*4 + r;
      if(row >= M) continue;
      #pragma unroll
      for(int jn = 0; jn < 4; ++jn){
        int col = n0 + wc*64 + jn*16 + lrow;
        float v = acc[i][jn][r];
        if constexpr (EPI == 0){
          Oz[(size_t)row*N + col] = f2bf(v);
        } else if constexpr (EPI == 1){
          float u = v*(0.7978845608f + 0.0356774081f*v*v);
          float t = 1.f - 2.f/(__expf(2.f*u) + 1.f);
          Oz[(size_t)row*N + col] = f2bf(0.5f*v*(1.f + t));
        } else {
          int bi = row / TPB, nnn = row - bi*TPB;
          size_t cat = (size_t)bi*387 + zb + nnn;
          float* dst = (float*)O + cat*CC + col;
          *dst += v;
        }
      }
    }
  }
}

// ---------------- 256x256 8-phase GEMM v2: ds_reads BEFORE the phase barrier ----------------
// 512 thr = 8 waves (2Mx4N), BK=64, 128KB LDS dbuf. Per tile: 4 phases, each
// {reads for this phase's MFMA | stage group for t+1 | barrier | MFMA | barrier}.
// All 8 stages issued in P0/P1; vmcnt(0) in P3 (~2 phases after issue -> near-free).
template<int EPI, int TPB>
__global__ __launch_bounds__(512, 1) void gemm8(
    const u16* __restrict__ A, size_t zsA,
    const u16* __restrict__ Bt, size_t zsB,
    void* __restrict__ O, size_t zsO,
    int M, int N, int K,
    int zoffmul)
{
  __shared__ u16 As[2][256*64];
  __shared__ u16 Bs[2][256*64];
  int z = blockIdx.z;
  const u16* Az = A + zsA*(size_t)z;
  const u16* Bz = Bt + zsB*(size_t)z;
  int bx, by; xcd_remap(gridDim.x, gridDim.y, bx, by);
  int m0 = bx*256, n0 = by*256;

  int tid = threadIdx.x, wid = tid >> 6, lane = tid & 63;
  int wr = wid >> 2, wc = wid & 3;
  int lrow = lane & 15, g4 = lane >> 4;

  int srow = tid >> 3;
  int swcol = ((tid & 7) ^ (srow & 7)) * 8;
  const u16 *pa[4], *pb[4];
  #pragma unroll
  for(int i = 0; i < 4; ++i){
    int ra = m0 + srow + i*64; ra = ra < M ? ra : M - 1;
    pa[i] = Az + (size_t)ra*K + swcol;
    pb[i] = Bz + (size_t)(n0 + srow + i*64)*K + swcol;
  }
  int dofs = tid*8;

  int xsk[2];
  xsk[0] = ((0*4 + g4) ^ (lrow & 7)) * 8;
  xsk[1] = ((1*4 + g4) ^ (lrow & 7)) * 8;

  // prologue: stage tile 0 into buf 0, drain, barrier
  #pragma unroll
  for(int i = 0; i < 4; ++i)
    __builtin_amdgcn_global_load_lds(AS1(pa[i]), AS3(&As[0][dofs + i*4096]), 16, 0, 0);
  #pragma unroll
  for(int i = 0; i < 4; ++i)
    __builtin_amdgcn_global_load_lds(AS1(pb[i]), AS3(&Bs[0][dofs + i*4096]), 16, 0, 0);
  #pragma unroll
  for(int i = 0; i < 4; ++i){ pa[i] += 64; pb[i] += 64; }
  asm volatile("s_waitcnt vmcnt(0)" ::: "memory");
  __builtin_amdgcn_s_barrier();

  f32x4 acc[8][4] = {};
  int NT = K >> 6;

  for(int t = 0; t < NT; ++t){
    int cur = t & 1, nx = cur ^ 1;
    bool pf = (t + 1 < NT);
    s16x8 aF[4][2], bL[2][2], bH[2][2];

    // ---- P0: reads(aF-M0, bL) | stage 4xA(t+1) | barrier | MFMA M0N0 | barrier
    #pragma unroll
    for(int mi = 0; mi < 4; ++mi)
      #pragma unroll
      for(int ks = 0; ks < 2; ++ks)
        aF[mi][ks] = *(const s16x8*)&As[cur][(wr*128 + mi*16 + lrow)*64 + xsk[ks]];
    #pragma unroll
    for(int ni = 0; ni < 2; ++ni)
      #pragma unroll
      for(int ks = 0; ks < 2; ++ks)
        bL[ni][ks] = *(const s16x8*)&Bs[cur][(wc*64 + ni*16 + lrow)*64 + xsk[ks]];
    if(pf){
      #pragma unroll
      for(int i = 0; i < 4; ++i)
        __builtin_amdgcn_global_load_lds(AS1(pa[i]), AS3(&As[nx][dofs + i*4096]), 16, 0, 0);
    }
    __builtin_amdgcn_s_barrier();
    __builtin_amdgcn_sched_barrier(0);
    __builtin_amdgcn_s_setprio(1);
    #pragma unroll
    for(int mi = 0; mi < 4; ++mi)
      #pragma unroll
      for(int ni = 0; ni < 2; ++ni)
        #pragma unroll
        for(int ks = 0; ks < 2; ++ks)
          acc[mi][ni] = mfma32(aF[mi][ks], bL[ni][ks], acc[mi][ni]);
    __builtin_amdgcn_s_setprio(0);
    __builtin_amdgcn_s_barrier();

    // ---- P1: reads(bH) | stage 4xB(t+1) | barrier | MFMA M0N1 | barrier
    #pragma unroll
    for(int ni = 0; ni < 2; ++ni)
      #pragma unroll
      for(int ks = 0; ks < 2; ++ks)
        bH[ni][ks] = *(const s16x8*)&Bs[cur][(wc*64 + (2+ni)*16 + lrow)*64 + xsk[ks]];
    if(pf){
      #pragma unroll
      for(int i = 0; i < 4; ++i)
        __builtin_amdgcn_global_load_lds(AS1(pb[i]), AS3(&Bs[nx][dofs + i*4096]), 16, 0, 0);
    }
    __builtin_amdgcn_s_barrier();
    __builtin_amdgcn_sched_barrier(0);
    __builtin_amdgcn_s_setprio(1);
    #pragma unroll
    for(int mi = 0; mi < 4; ++mi)
      #pragma unroll
      for(int ni = 0; ni < 2; ++ni)
        #pragma unroll
        for(int ks = 0; ks < 2; ++ks)
          acc[mi][2+ni] = mfma32(aF[mi][ks], bH[ni][ks], acc[mi][2+ni]);
    __builtin_amdgcn_s_setprio(0);
    __builtin_amdgcn_s_barrier();

    // ---- P2: reads(aF-M1) | barrier | MFMA M1N1 | barrier
    #pragma unroll
    for(int mi = 0; mi < 4; ++mi)
      #pragma unroll
      for(int ks = 0; ks < 2; ++ks)
        aF[mi][ks] = *(const s16x8*)&As[cur][(wr*128 + (4+mi)*16 + lrow)*64 + xsk[ks]];
    __builtin_amdgcn_s_barrier();
    __builtin_amdgcn_sched_barrier(0);
    __builtin_amdgcn_s_setprio(1);
    #pragma unroll
    for(int mi = 0; mi < 4; ++mi)
      #pragma unroll
      for(int ni = 0; ni < 2; ++ni)
        #pragma unroll
        for(int ks = 0; ks < 2; ++ks)
          acc[4+mi][2+ni] = mfma32(aF[mi][ks], bH[ni][ks], acc[4+mi][2+ni]);
    __builtin_amdgcn_s_setprio(0);
    __builtin_amdgcn_s_barrier();

    // ---- P3: advance ptrs, vmcnt(0) (loads issued ~2 phases ago) | barrier | MFMA M1N0 | barrier
    if(pf){
      #pragma unroll
      for(int i = 0; i < 4; ++i){ pa[i] += 64; pb[i] += 64; }
      asm volatile("s_waitcnt vmcnt(0)" ::: "memory");
    }
    __builtin_amdgcn_s_barrier();
    __builtin_amdgcn_sched_barrier(0);
    __builtin_amdgcn_s_setprio(1);
    #pragma unroll
    for(int mi = 0; mi < 4; ++mi)
      #pragma unroll
      for(int ni = 0; ni < 2; ++ni)
        #pragma unroll
        for(int ks = 0; ks < 2; ++ks)
          acc[4+mi][ni] = mfma32(aF[mi][ks], bL[ni][ks], acc[4+mi][ni]);
    __builtin_amdgcn_s_setprio(0);
    __builtin_amdgcn_s_barrier();
  }

  u16* Oz = (u16*)O + zsO*(size_t)z;
  int zb = z*zoffmul;
  #pragma unroll
  for(int mi = 0; mi < 8; ++mi){
    #pragma unroll
    for(int r = 0; r < 4; ++r){
      int row = m0 + wr*128 + mi*16 + g4*4 + r;
      if(row >= M) continue;
      #pragma unroll
      for(int ni = 0; ni < 4; ++ni){
        int col = n0 + wc*64 + ni*16 + lrow;
        float v = acc[mi][ni][r];
        if constexpr (EPI == 0){
          Oz[(size_t)row*N + col] = f2bf(v);
        } else if constexpr (EPI == 1){
          float u = v*(0.7978845608f + 0.0356774081f*v*v);
          float t = 1.f - 2.f/(__expf(2.f*u) + 1.f);
          Oz[(size_t)row*N + col] = f2bf(0.5f*v*(1.f + t));
        } else {
          int bi = row / TPB, nnn = row - bi*TPB;
          size_t cat = (size_t)bi*387 + zb + nnn;
          float* dst = (float*)O + cat*CC + col;
          *dst += v;
        }
      }
    }
  }
}

// ---------------- attention v4 (r13-verified) ----------------
template<int N_>
__global__ __launch_bounds__(256) void attn3(
    const u16* __restrict__ qkv, size_t zsQ,
    u16* __restrict__ out, size_t zsO,
    const float* __restrict__ mask)
{
  constexpr int NC  = (N_ + 63)/64;
  constexpr int NKC = NC*64;
  constexpr float SCL = 0.125f*1.44269504088896f;
  __shared__ u16 Ks[2][64][66];
  __shared__ u16 Vt[2][64][68];
  __shared__ float Msk[NKC];

  int z = blockIdx.z;
  int bh = blockIdx.y, b = bh / HH, hh = bh - b*HH;
  int tid = threadIdx.x, wid = tid >> 6, lane = tid & 63;
  int lq = lane & 15, g = lane >> 4;
  const u16* qz = qkv + zsQ*(size_t)z;
  const size_t rowbase = (size_t)b*N_;
  const u16* kbase = qz + rowbase*2304 + 768 + hh*64;
  const u16* vbase = kbase + 768;

  for(int k = tid; k < NKC; k += 256){
    float mk = 0.f;
    if(k < N_){ int nn = (N_ > 129) ? (k % 129) : k; mk = (nn == 0) ? 1.f : mask[b*128 + nn - 1]; }
    Msk[k] = (mk != 0.f) ? 0.f : -1e30f;
  }

  int q0[2]; s16x8 qF0[2], qF1[2];
  #pragma unroll
  for(int qi = 0; qi < 2; ++qi){
    q0[qi] = blockIdx.x*128 + qi*64 + wid*16;
    int qrow = q0[qi] + lq;
    int qrc = qrow < N_ ? qrow : N_ - 1;
    const u16* qptr = qz + (rowbase + qrc)*2304 + hh*64;
    qF0[qi] = *(const s16x8*)(qptr + g*8);
    qF1[qi] = *(const s16x8*)(qptr + 32 + g*8);
  }

  int r0 = tid >> 3, c16 = tid & 7;
  s16x8 kr[2], vr[2];
  const s16x8 zv = {0,0,0,0,0,0,0,0};

  #pragma unroll
  for(int i = 0; i < 2; ++i){
    int row = r0 + i*32;
    kr[i] = (row < N_) ? *(const s16x8*)(kbase + (size_t)row*2304 + c16*8) : zv;
    vr[i] = (row < N_) ? *(const s16x8*)(vbase + (size_t)row*2304 + c16*8) : zv;
  }
  #pragma unroll
  for(int i = 0; i < 2; ++i){
    *(s16x8*)&Ks[0][r0 + i*32][c16*8] = kr[i];
    #pragma unroll
    for(int j = 0; j < 8; ++j) Vt[0][c16*8 + j][r0 + i*32] = (u16)vr[i][j];
  }
  __syncthreads();

  f32x4 o[2][4] = {};
  float l[2] = {0.f, 0.f};

  for(int ch = 0; ch < NC; ++ch){
    int cur = ch & 1;
    if(ch + 1 < NC){
      #pragma unroll
      for(int i = 0; i < 2; ++i){
        int row = (ch + 1)*64 + r0 + i*32;
        kr[i] = (row < N_) ? *(const s16x8*)(kbase + (size_t)row*2304 + c16*8) : zv;
        vr[i] = (row < N_) ? *(const s16x8*)(vbase + (size_t)row*2304 + c16*8) : zv;
      }
    }
    #pragma unroll
    for(int qi = 0; qi < 2; ++qi){
      float pT[4][4];
      #pragma unroll
      for(int t = 0; t < 4; ++t){
        s16x8 kF0 = *(const s16x8*)&Ks[cur][t*16 + lq][g*8];
        s16x8 kF1 = *(const s16x8*)&Ks[cur][t*16 + lq][32 + g*8];
        f32x4 s = {0.f,0.f,0.f,0.f};
        s = mfma32(kF0, qF0[qi], s);
        s = mfma32(kF1, qF1[qi], s);
        const float* mrow = &Msk[ch*64 + t*16 + g*4];
        #pragma unroll
        for(int r = 0; r < 4; ++r){
          float p = exp2f(fmaf(s[r], SCL, mrow[r]));
          pT[t][r] = p;
          l[qi] += p;
        }
      }
      #pragma unroll
      for(int t = 0; t < 4; ++t){
        s16x4 pa;
        #pragma unroll
        for(int r = 0; r < 4; ++r) pa[r] = (short)f2bf(pT[t][r]);
        #pragma unroll
        for(int db = 0; db < 4; ++db){
          s16x4 vf = *(const s16x4*)&Vt[cur][db*16 + lq][t*16 + g*4];
          o[qi][db] = mfma16(pa, vf, o[qi][db]);
        }
      }
    }
    if(ch + 1 < NC){
      int nxt = (ch + 1) & 1;
      #pragma unroll
      for(int i = 0; i < 2; ++i){
        *(s16x8*)&Ks[nxt][r0 + i*32][c16*8] = kr[i];
        #pragma unroll
        for(int j = 0; j < 8; ++j) Vt[nxt][c16*8 + j][r0 + i*32] = (u16)vr[i][j];
      }
      __syncthreads();
    }
  }

  #pragma unroll
  for(int qi = 0; qi < 2; ++qi){
    float lv = l[qi];
    lv += __shfl_xor(lv, 16);
    lv += __shfl_xor(lv, 32);
    int qrow = q0[qi] + lq;
    float mq = 0.f;
    if(qrow < N_) mq = (Msk[qrow] == 0.f) ? 1.f : 0.f;
    float sc = mq / lv;
    float scr[4];
    #pragma unroll
    for(int r = 0; r < 4; ++r) scr[r] = __shfl(sc, g*4 + r);
    #pragma unroll
    for(int db = 0; db < 4; ++db){
      #pragma unroll
      for(int r = 0; r < 4; ++r){
        int qq = q0[qi] + g*4 + r;
        if(qq < N_)
          out[zsO*(size_t)z + (rowbase + qq)*CC + hh*64 + db*16 + lq] = f2bf(o[qi][db][r]*scr[r]);
      }
    }
  }
}

extern "C" void kernel_launch(void* const* d_in, const int* in_sizes, int n_in,
                              void* d_out, int out_size, void* d_ws, size_t ws_size,
                              hipStream_t stream)
{
  const float* RGB   = (const float*)d_in[0];
  const float* NIR   = (const float*)d_in[1];
  const float* TIR   = (const float*)d_in[2];
  const float* mask  = (const float*)d_in[3];
  const float* ln_g1 = (const float*)d_in[5];
  const float* ln_b1 = (const float*)d_in[6];
  const float* w_qkv = (const float*)d_in[7];
  const float* w_proj= (const float*)d_in[8];
  const float* ln_g2 = (const float*)d_in[9];
  const float* ln_b2 = (const float*)d_in[10];
  const float* w_fc1 = (const float*)d_in[11];
  const float* w_fc2 = (const float*)d_in[12];
  const float* out_g = (const float*)d_in[13];
  const float* out_b = (const float*)d_in[14];

  char* p = (char*)d_ws;
  u16* wqkv_t  = (u16*)p; p += (size_t)4*2304*768*2;
  u16* wproj_t = (u16*)p; p += (size_t)4*768*768*2;
  u16* w1_t    = (u16*)p; p += (size_t)4*768*3072*2;
  u16* w2_t    = (u16*)p; p += (size_t)4*3072*768*2;
  float* xcat  = (float*)p; p += (size_t)12384*768*4;
  u16* xm      = (u16*)p; p += (size_t)3*4224*768*2;
  u16* qkv     = (u16*)p; p += (size_t)3*4224*3072*2;
  u16* hbuf    = qkv;
  if((size_t)(p - (char*)d_ws) > ws_size) return;

  wtrans<<<dim3(24, 72, 4), 256, 0, stream>>>(w_qkv, wqkv_t, 768, 2304);
  wtrans<<<dim3(24, 24, 4), 256, 0, stream>>>(w_proj, wproj_t, 768, 768);
  wtrans<<<dim3(24, 96, 4), 256, 0, stream>>>(w_fc1, w1_t, 768, 3072);
  wtrans<<<dim3(96, 24, 4), 256, 0, stream>>>(w_fc2, w2_t, 3072, 768);
  initcat<<<dim3(3096, 3), 256, 0, stream>>>(RGB, NIR, TIR, xcat);

  const int M3 = 4128;
  const size_t zxm = (size_t)4224*768, zqkv = (size_t)4224*2304, zh = (size_t)4224*3072;
  // ---- branches 0..2 ----
  ln_mask<0><<<dim3(M3/4,3), 256, 0, stream>>>(xcat, ln_g1, ln_b1, 768, mask, xm, zxm, 129, 129);
  gemm8<0,1><<<dim3(17,9,3), 512, 0, stream>>>(xm, zxm, wqkv_t, (size_t)2304*768, qkv, zqkv, M3, 2304, 768, 0);
  attn3<129><<<dim3(2,384,3), 256, 0, stream>>>(qkv, zqkv, xm, zxm, mask);
  gemm_bt<2,129><<<dim3(33,6,3), 256, 0, stream>>>(xm, zxm, wproj_t, (size_t)768*768, xcat, 0, M3, 768, 768, 129);
  ln_mask<0><<<dim3(M3/4,3), 256, 0, stream>>>(xcat, ln_g2, ln_b2, 768, mask, xm, zxm, 129, 129);
  gemm8<1,1><<<dim3(17,12,3), 512, 0, stream>>>(xm, zxm, w1_t, (size_t)768*3072, hbuf, zh, M3, 3072, 768, 0);
  gemm8<2,129><<<dim3(17,3,3), 512, 0, stream>>>(hbuf, zh, w2_t, (size_t)768*3072, xcat, 0, M3, 768, 3072, 129);
  // ---- concat branch ----
  const int M1 = 12384;
  ln_mask<0><<<dim3(M1/4,1), 256, 0, stream>>>(xcat, ln_g1 + 3*768, ln_b1 + 3*768, 0, mask, xm, 0, 387, 0);
  gemm8<0,1><<<dim3(49,9,1), 512, 0, stream>>>(xm, 0, wqkv_t + (size_t)3*2304*768, 0, qkv, 0, M1, 2304, 768, 0);
  attn3<387><<<dim3(4,384,1), 256, 0, stream>>>(qkv, 0, xm, 0, mask);
  gemm_bt<2,387><<<dim3(97,6,1), 256, 0, stream>>>(xm, 0, wproj_t + (size_t)3*768*768, 0, xcat, 0, M1, 768, 768, 0);
  ln_mask<0><<<dim3(M1/4,1), 256, 0, stream>>>(xcat, ln_g2 + 3*768, ln_b2 + 3*768, 0, mask, xm, 0, 387, 0);
  gemm8<1,1><<<dim3(49,12,1), 512, 0, stream>>>(xm, 0, w1_t + (size_t)3*768*3072, 0, hbuf, 0, M1, 3072, 768, 0);
  gemm8<2,387><<<dim3(49,3,1), 512, 0, stream>>>(hbuf, 0, w2_t + (size_t)3*768*3072, 0, xcat, 0, M1, 768, 3072, 0);
  // ---- final LN ----
  ln_mask<1><<<dim3(M1/4,1), 256, 0, stream>>>(xcat, out_g, out_b, 0, mask, d_out, 0, 387, 0);
}

// Round 17
// 711.044 us; speedup vs baseline: 2.0036x; 1.1627x over previous
//
#include <hip/hip_runtime.h>

typedef unsigned short u16;
typedef __attribute__((ext_vector_type(4))) float f32x4;
typedef __attribute__((ext_vector_type(8))) short s16x8;
typedef __attribute__((ext_vector_type(4))) short s16x4;
typedef __attribute__((ext_vector_type(4))) unsigned short u16x4;

#define HH 12
#define CC 768
#define AS1(p) ((const __attribute__((address_space(1))) void*)(p))
#define AS3(p) ((__attribute__((address_space(3))) void*)(p))

__device__ inline u16 f2bf(float x){
  unsigned u = __float_as_uint(x);
  u = (u + 0x7FFFu + ((u >> 16) & 1u)) >> 16;
  return (u16)u;
}

__device__ inline f32x4 mfma32(s16x8 a, s16x8 b, f32x4 c){
  return __builtin_amdgcn_mfma_f32_16x16x32_bf16(a, b, c, 0, 0, 0);
}
__device__ inline f32x4 mfma16(s16x4 a, s16x4 b, f32x4 c){
  return __builtin_amdgcn_mfma_f32_16x16x16bf16_1k(a, b, c, 0, 0, 0);
}

__device__ inline void xcd_remap(int gx, int gy, int& bx, int& by){
  int nwg = gx*gy;
  int orig = blockIdx.x + gx*blockIdx.y;
  int q = nwg >> 3, r8 = nwg & 7;
  int xcd = orig & 7, off = orig >> 3;
  int wg = (xcd < r8 ? xcd*(q+1) : r8*(q+1) + (xcd-r8)*q) + off;
  bx = wg / gy; by = wg - bx*gy;
}

// ---------------- weight fp32 [K,N] -> bf16 [N,K] (per blockIdx.z set) ----------------
__global__ void wtrans(const float* __restrict__ W, u16* __restrict__ Wt, int K, int N){
  __shared__ float tile[32][33];
  int k0 = blockIdx.x*32, n0 = blockIdx.y*32;
  const float* Wz = W + (size_t)blockIdx.z*K*N;
  u16* Wtz = Wt + (size_t)blockIdx.z*K*N;
  int tx = threadIdx.x & 31, ty = threadIdx.x >> 5;
  #pragma unroll
  for(int r = ty; r < 32; r += 8)
    tile[r][tx] = Wz[(size_t)(k0+r)*N + n0 + tx];
  __syncthreads();
  #pragma unroll
  for(int r = ty; r < 32; r += 8)
    Wtz[(size_t)(n0+r)*K + k0 + tx] = f2bf(tile[tx][r]);
}

// ---------------- scatter RGB/NIR/TIR into concat layout [B,387,C] ----------------
__global__ void initcat(const float* __restrict__ R, const float* __restrict__ Nr,
                        const float* __restrict__ T, float* __restrict__ xcat){
  int idx = blockIdx.x*256 + threadIdx.x;
  const int per = 32*129*768/4;
  if(idx >= per) return;
  int z = blockIdx.y;
  const float* src = z == 0 ? R : (z == 1 ? Nr : T);
  float4 v = ((const float4*)src)[idx];
  int e = idx*4;
  int row = e / 768, c = e - row*768;
  int bb2 = row / 129, nn = row - bb2*129;
  ((float4*)xcat)[((size_t)(bb2*387 + z*129 + nn)*768 + c)/4] = v;
}

__device__ inline float maskval(const float* m, int b, int n){
  return (n == 0) ? 1.0f : m[b*128 + n - 1];
}

// ---------------- LayerNorm * mask : 4 rows per 256-thr block ----------------
template<int F32OUT>
__global__ __launch_bounds__(256) void ln_mask(
    const float* __restrict__ x,
    const float* __restrict__ gg, const float* __restrict__ bb, int zsG,
    const float* __restrict__ mask,
    void* __restrict__ out, size_t zsO,
    int tpb, int zoffmul)
{
  int wid = threadIdx.x >> 6, lane = threadIdx.x & 63;
  int r = blockIdx.x*4 + wid, z = blockIdx.y;
  int bidx = r / tpb, nn = r - bidx*tpb;
  size_t cat = (size_t)bidx*387 + z*zoffmul + nn;
  const float4* xr = (const float4*)(x + cat*CC);
  float4 v[3]; float s = 0.f, sq = 0.f;
  #pragma unroll
  for(int w = 0; w < 3; ++w){
    v[w] = xr[w*64 + lane];
    s  += v[w].x + v[w].y + v[w].z + v[w].w;
    sq += v[w].x*v[w].x + v[w].y*v[w].y + v[w].z*v[w].z + v[w].w*v[w].w;
  }
  #pragma unroll
  for(int o = 32; o; o >>= 1){ s += __shfl_xor(s, o); sq += __shfl_xor(sq, o); }
  float mu = s * (1.f/768.f);
  float var = sq * (1.f/768.f) - mu*mu;
  float rstd = rsqrtf(var + 1e-5f);
  float mv = maskval(mask, bidx, nn % 129);
  const float4* g4 = (const float4*)(gg + (size_t)z*zsG);
  const float4* b4 = (const float4*)(bb + (size_t)z*zsG);
  #pragma unroll
  for(int w = 0; w < 3; ++w){
    float4 gv = g4[w*64+lane], bv = b4[w*64+lane];
    float y0 = ((v[w].x - mu)*rstd*gv.x + bv.x) * mv;
    float y1 = ((v[w].y - mu)*rstd*gv.y + bv.y) * mv;
    float y2 = ((v[w].z - mu)*rstd*gv.z + bv.z) * mv;
    float y3 = ((v[w].w - mu)*rstd*gv.w + bv.w) * mv;
    if(F32OUT){
      ((float4*)out)[cat*(CC/4) + w*64 + lane] = make_float4(y0,y1,y2,y3);
    } else {
      u16x4 p; p.x = f2bf(y0); p.y = f2bf(y1); p.z = f2bf(y2); p.w = f2bf(y3);
      ((u16x4*)((u16*)out + z*zsO + (size_t)r*CC))[w*64 + lane] = p;
    }
  }
}

// ---------------- GEMM 128x128 (single-buf BK=64, T2 swizzle, high TLP) ----------------
// EPI 0: bf16 store ; 1: tanh-gelu bf16 ; 2: residual-add fp32 xcat (strided)
// launch_bounds (256,4): VGPR cap 128 -> no spill (acc needs 64+); (256,5) spilled (r14).
template<int EPI, int TPB>
__global__ __launch_bounds__(256, 4) void gemm_bt(
    const u16* __restrict__ A, size_t zsA,
    const u16* __restrict__ Bt, size_t zsB,
    void* __restrict__ O, size_t zsO,
    int M, int N, int K,
    int zoffmul)
{
  __shared__ u16 As[128*64];
  __shared__ u16 Bs[128*64];
  int z = blockIdx.z;
  const u16* Az = A + zsA*(size_t)z;
  const u16* Bz = Bt + zsB*(size_t)z;
  int bx, by; xcd_remap(gridDim.x, gridDim.y, bx, by);
  int m0 = bx*128, n0 = by*128;

  int tid = threadIdx.x, wid = tid >> 6, lane = tid & 63;
  int wr = wid >> 1, wc = wid & 1;
  int lrow = lane & 15, g4 = lane >> 4;

  int srow = tid >> 3;
  int swcol = ((tid & 7) ^ (srow & 7)) * 8;
  const u16 *pa[4], *pb[4];
  #pragma unroll
  for(int i = 0; i < 4; ++i){
    int ra = m0 + srow + i*32; ra = ra < M ? ra : M - 1;
    pa[i] = Az + (size_t)ra*K + swcol;
    pb[i] = Bz + (size_t)(n0 + srow + i*32)*K + swcol;
  }
  int dofs = tid*8;
  int xs0 = ((0*4 + g4) ^ (lrow & 7)) * 8;
  int xs1 = ((1*4 + g4) ^ (lrow & 7)) * 8;

  f32x4 acc[4][4] = {};
  int NT = K >> 6;

  for(int t = 0; t < NT; ++t){
    #pragma unroll
    for(int i = 0; i < 4; ++i)
      __builtin_amdgcn_global_load_lds(AS1(pa[i]), AS3(&As[dofs + i*2048]), 16, 0, 0);
    #pragma unroll
    for(int i = 0; i < 4; ++i)
      __builtin_amdgcn_global_load_lds(AS1(pb[i]), AS3(&Bs[dofs + i*2048]), 16, 0, 0);
    #pragma unroll
    for(int i = 0; i < 4; ++i){ pa[i] += 64; pb[i] += 64; }
    __syncthreads();
    #pragma unroll
    for(int kk = 0; kk < 2; ++kk){
      int xs = kk ? xs1 : xs0;
      s16x8 aF[4], bF[4];
      #pragma unroll
      for(int i = 0; i < 4; ++i){
        aF[i] = *(const s16x8*)&As[(wr*64 + i*16 + lrow)*64 + xs];
        bF[i] = *(const s16x8*)&Bs[(wc*64 + i*16 + lrow)*64 + xs];
      }
      #pragma unroll
      for(int i = 0; i < 4; ++i)
        #pragma unroll
        for(int jn = 0; jn < 4; ++jn)
          acc[i][jn] = mfma32(aF[i], bF[jn], acc[i][jn]);
    }
    __syncthreads();
  }

  u16* Oz = (u16*)O + zsO*(size_t)z;
  int zb = z*zoffmul;
  #pragma unroll
  for(int i = 0; i < 4; ++i){
    #pragma unroll
    for(int r = 0; r < 4; ++r){
      int row = m0 + wr*64 + i*16 + g4*4 + r;
      if(row >= M) continue;
      #pragma unroll
      for(int jn = 0; jn < 4; ++jn){
        int col = n0 + wc*64 + jn*16 + lrow;
        float v = acc[i][jn][r];
        if constexpr (EPI == 0){
          Oz[(size_t)row*N + col] = f2bf(v);
        } else if constexpr (EPI == 1){
          float u = v*(0.7978845608f + 0.0356774081f*v*v);
          float t = 1.f - 2.f/(__expf(2.f*u) + 1.f);
          Oz[(size_t)row*N + col] = f2bf(0.5f*v*(1.f + t));
        } else {
          int bi = row / TPB, nnn = row - bi*TPB;
          size_t cat = (size_t)bi*387 + zb + nnn;
          float* dst = (float*)O + cat*CC + col;
          *dst += v;
        }
      }
    }
  }
}

// ---------------- attention v4: 128 q-rows/block (2 q-tiles per wave), K/V staged once ----------------
template<int N_>
__global__ __launch_bounds__(256) void attn3(
    const u16* __restrict__ qkv, size_t zsQ,
    u16* __restrict__ out, size_t zsO,
    const float* __restrict__ mask)
{
  constexpr int NC  = (N_ + 63)/64;
  constexpr int NKC = NC*64;
  constexpr float SCL = 0.125f*1.44269504088896f;
  __shared__ u16 Ks[2][64][66];
  __shared__ u16 Vt[2][64][68];
  __shared__ float Msk[NKC];

  int z = blockIdx.z;
  int bh = blockIdx.y, b = bh / HH, hh = bh - b*HH;
  int tid = threadIdx.x, wid = tid >> 6, lane = tid & 63;
  int lq = lane & 15, g = lane >> 4;
  const u16* qz = qkv + zsQ*(size_t)z;
  const size_t rowbase = (size_t)b*N_;
  const u16* kbase = qz + rowbase*2304 + 768 + hh*64;
  const u16* vbase = kbase + 768;

  for(int k = tid; k < NKC; k += 256){
    float mk = 0.f;
    if(k < N_){ int nn = (N_ > 129) ? (k % 129) : k; mk = (nn == 0) ? 1.f : mask[b*128 + nn - 1]; }
    Msk[k] = (mk != 0.f) ? 0.f : -1e30f;
  }

  int q0[2]; s16x8 qF0[2], qF1[2];
  #pragma unroll
  for(int qi = 0; qi < 2; ++qi){
    q0[qi] = blockIdx.x*128 + qi*64 + wid*16;
    int qrow = q0[qi] + lq;
    int qrc = qrow < N_ ? qrow : N_ - 1;
    const u16* qptr = qz + (rowbase + qrc)*2304 + hh*64;
    qF0[qi] = *(const s16x8*)(qptr + g*8);
    qF1[qi] = *(const s16x8*)(qptr + 32 + g*8);
  }

  int r0 = tid >> 3, c16 = tid & 7;
  s16x8 kr[2], vr[2];
  const s16x8 zv = {0,0,0,0,0,0,0,0};

  #pragma unroll
  for(int i = 0; i < 2; ++i){
    int row = r0 + i*32;
    kr[i] = (row < N_) ? *(const s16x8*)(kbase + (size_t)row*2304 + c16*8) : zv;
    vr[i] = (row < N_) ? *(const s16x8*)(vbase + (size_t)row*2304 + c16*8) : zv;
  }
  #pragma unroll
  for(int i = 0; i < 2; ++i){
    *(s16x8*)&Ks[0][r0 + i*32][c16*8] = kr[i];
    #pragma unroll
    for(int j = 0; j < 8; ++j) Vt[0][c16*8 + j][r0 + i*32] = (u16)vr[i][j];
  }
  __syncthreads();

  f32x4 o[2][4] = {};
  float l[2] = {0.f, 0.f};

  for(int ch = 0; ch < NC; ++ch){
    int cur = ch & 1;
    if(ch + 1 < NC){
      #pragma unroll
      for(int i = 0; i < 2; ++i){
        int row = (ch + 1)*64 + r0 + i*32;
        kr[i] = (row < N_) ? *(const s16x8*)(kbase + (size_t)row*2304 + c16*8) : zv;
        vr[i] = (row < N_) ? *(const s16x8*)(vbase + (size_t)row*2304 + c16*8) : zv;
      }
    }
    #pragma unroll
    for(int qi = 0; qi < 2; ++qi){
      float pT[4][4];
      #pragma unroll
      for(int t = 0; t < 4; ++t){
        s16x8 kF0 = *(const s16x8*)&Ks[cur][t*16 + lq][g*8];
        s16x8 kF1 = *(const s16x8*)&Ks[cur][t*16 + lq][32 + g*8];
        f32x4 s = {0.f,0.f,0.f,0.f};
        s = mfma32(kF0, qF0[qi], s);
        s = mfma32(kF1, qF1[qi], s);
        const float* mrow = &Msk[ch*64 + t*16 + g*4];
        #pragma unroll
        for(int r = 0; r < 4; ++r){
          float p = exp2f(fmaf(s[r], SCL, mrow[r]));
          pT[t][r] = p;
          l[qi] += p;
        }
      }
      #pragma unroll
      for(int t = 0; t < 4; ++t){
        s16x4 pa;
        #pragma unroll
        for(int r = 0; r < 4; ++r) pa[r] = (short)f2bf(pT[t][r]);
        #pragma unroll
        for(int db = 0; db < 4; ++db){
          s16x4 vf = *(const s16x4*)&Vt[cur][db*16 + lq][t*16 + g*4];
          o[qi][db] = mfma16(pa, vf, o[qi][db]);
        }
      }
    }
    if(ch + 1 < NC){
      int nxt = (ch + 1) & 1;
      #pragma unroll
      for(int i = 0; i < 2; ++i){
        *(s16x8*)&Ks[nxt][r0 + i*32][c16*8] = kr[i];
        #pragma unroll
        for(int j = 0; j < 8; ++j) Vt[nxt][c16*8 + j][r0 + i*32] = (u16)vr[i][j];
      }
      __syncthreads();
    }
  }

  #pragma unroll
  for(int qi = 0; qi < 2; ++qi){
    float lv = l[qi];
    lv += __shfl_xor(lv, 16);
    lv += __shfl_xor(lv, 32);
    int qrow = q0[qi] + lq;
    float mq = 0.f;
    if(qrow < N_) mq = (Msk[qrow] == 0.f) ? 1.f : 0.f;
    float sc = mq / lv;
    float scr[4];
    #pragma unroll
    for(int r = 0; r < 4; ++r) scr[r] = __shfl(sc, g*4 + r);
    #pragma unroll
    for(int db = 0; db < 4; ++db){
      #pragma unroll
      for(int r = 0; r < 4; ++r){
        int qq = q0[qi] + g*4 + r;
        if(qq < N_)
          out[zsO*(size_t)z + (rowbase + qq)*CC + hh*64 + db*16 + lq] = f2bf(o[qi][db][r]*scr[r]);
      }
    }
  }
}

extern "C" void kernel_launch(void* const* d_in, const int* in_sizes, int n_in,
                              void* d_out, int out_size, void* d_ws, size_t ws_size,
                              hipStream_t stream)
{
  const float* RGB   = (const float*)d_in[0];
  const float* NIR   = (const float*)d_in[1];
  const float* TIR   = (const float*)d_in[2];
  const float* mask  = (const float*)d_in[3];
  const float* ln_g1 = (const float*)d_in[5];
  const float* ln_b1 = (const float*)d_in[6];
  const float* w_qkv = (const float*)d_in[7];
  const float* w_proj= (const float*)d_in[8];
  const float* ln_g2 = (const float*)d_in[9];
  const float* ln_b2 = (const float*)d_in[10];
  const float* w_fc1 = (const float*)d_in[11];
  const float* w_fc2 = (const float*)d_in[12];
  const float* out_g = (const float*)d_in[13];
  const float* out_b = (const float*)d_in[14];

  char* p = (char*)d_ws;
  u16* wqkv_t  = (u16*)p; p += (size_t)4*2304*768*2;
  u16* wproj_t = (u16*)p; p += (size_t)4*768*768*2;
  u16* w1_t    = (u16*)p; p += (size_t)4*768*3072*2;
  u16* w2_t    = (u16*)p; p += (size_t)4*3072*768*2;
  float* xcat  = (float*)p; p += (size_t)12384*768*4;
  u16* xm      = (u16*)p; p += (size_t)3*4224*768*2;
  u16* qkv     = (u16*)p; p += (size_t)3*4224*3072*2;
  u16* hbuf    = qkv;
  if((size_t)(p - (char*)d_ws) > ws_size) return;

  wtrans<<<dim3(24, 72, 4), 256, 0, stream>>>(w_qkv, wqkv_t, 768, 2304);
  wtrans<<<dim3(24, 24, 4), 256, 0, stream>>>(w_proj, wproj_t, 768, 768);
  wtrans<<<dim3(24, 96, 4), 256, 0, stream>>>(w_fc1, w1_t, 768, 3072);
  wtrans<<<dim3(96, 24, 4), 256, 0, stream>>>(w_fc2, w2_t, 3072, 768);
  initcat<<<dim3(3096, 3), 256, 0, stream>>>(RGB, NIR, TIR, xcat);

  const int M3 = 4128;
  const size_t zxm = (size_t)4224*768, zqkv = (size_t)4224*2304, zh = (size_t)4224*3072;
  // ---- branches 0..2 ----
  ln_mask<0><<<dim3(M3/4,3), 256, 0, stream>>>(xcat, ln_g1, ln_b1, 768, mask, xm, zxm, 129, 129);
  gemm_bt<0,1><<<dim3(33,18,3), 256, 0, stream>>>(xm, zxm, wqkv_t, (size_t)2304*768, qkv, zqkv, M3, 2304, 768, 0);
  attn3<129><<<dim3(2,384,3), 256, 0, stream>>>(qkv, zqkv, xm, zxm, mask);
  gemm_bt<2,129><<<dim3(33,6,3), 256, 0, stream>>>(xm, zxm, wproj_t, (size_t)768*768, xcat, 0, M3, 768, 768, 129);
  ln_mask<0><<<dim3(M3/4,3), 256, 0, stream>>>(xcat, ln_g2, ln_b2, 768, mask, xm, zxm, 129, 129);
  gemm_bt<1,1><<<dim3(33,24,3), 256, 0, stream>>>(xm, zxm, w1_t, (size_t)768*3072, hbuf, zh, M3, 3072, 768, 0);
  gemm_bt<2,129><<<dim3(33,6,3), 256, 0, stream>>>(hbuf, zh, w2_t, (size_t)768*3072, xcat, 0, M3, 768, 3072, 129);
  // ---- concat branch ----
  const int M1 = 12384;
  ln_mask<0><<<dim3(M1/4,1), 256, 0, stream>>>(xcat, ln_g1 + 3*768, ln_b1 + 3*768, 0, mask, xm, 0, 387, 0);
  gemm_bt<0,1><<<dim3(97,18,1), 256, 0, stream>>>(xm, 0, wqkv_t + (size_t)3*2304*768, 0, qkv, 0, M1, 2304, 768, 0);
  attn3<387><<<dim3(4,384,1), 256, 0, stream>>>(qkv, 0, xm, 0, mask);
  gemm_bt<2,387><<<dim3(97,6,1), 256, 0, stream>>>(xm, 0, wproj_t + (size_t)3*768*768, 0, xcat, 0, M1, 768, 768, 0);
  ln_mask<0><<<dim3(M1/4,1), 256, 0, stream>>>(xcat, ln_g2 + 3*768, ln_b2 + 3*768, 0, mask, xm, 0, 387, 0);
  gemm_bt<1,1><<<dim3(97,24,1), 256, 0, stream>>>(xm, 0, w1_t + (size_t)3*768*3072, 0, hbuf, 0, M1, 3072, 768, 0);
  gemm_bt<2,387><<<dim3(97,6,1), 256, 0, stream>>>(hbuf, 0, w2_t + (size_t)3*768*3072, 0, xcat, 0, M1, 768, 3072, 0);
  // ---- final LN ----
  ln_mask<1><<<dim3(M1/4,1), 256, 0, stream>>>(xcat, out_g, out_b, 0, mask, d_out, 0, 387, 0);
}